// Round 3
// baseline (222.982 us; speedup 1.0000x reference)
//
#include <hip/hip_runtime.h>

// MMD RBF loss, N=8192, D=128, gamma=1, fp32 in, fp32 scalar out.
// R3: barrier-free. One wave = one 64x64 tile strip. A-frags + damMax in
// registers; B-frags direct from L2 with 4-slot register rotation, 2 K-steps
// of prefetch. 32x32x16 bf16 MFMA (2x2 frags, 8 K-steps). Thresholded
// epilogue: per-frag conservative max test; exact norms + exp only on
// (near-)diagonal tiles. No LDS, no __syncthreads in the hot kernel.

#define N_PTS 8192
#define TJ 128              // 8192/64 col tiles per side
#define NSELF 8256          // 128*129/2
#define NT 32896            // 2*NSELF + 128*128
#define NBLOCKS 1024
#define NWAVES (NBLOCKS * 4)
#define LOG2E 1.4426950408889634f
#define THRESH -40.0f

typedef __attribute__((ext_vector_type(8))) short short8;    // 8 bf16
typedef __attribute__((ext_vector_type(16))) float floatx16; // 32x32 acc
typedef unsigned int u32;
typedef unsigned short u16;

#if __has_builtin(__builtin_amdgcn_exp2f)
#define EXP2(x) __builtin_amdgcn_exp2f(x)
#else
#define EXP2(x) exp2f(x)
#endif

__device__ __forceinline__ u16 f32_to_bf16(float f) {
  u32 u = __float_as_uint(f);
  u32 r = (u + 0x7fffu + ((u >> 16) & 1u)) >> 16;  // RNE
  return (u16)r;
}

// ---- prep: fp32 -> bf16 (RNE) + per-row d = -log2e*sum(xb^2); zero S/cnt ----
__global__ void prep_kernel(const float* __restrict__ x, const float* __restrict__ y,
                            u32* __restrict__ xb, u32* __restrict__ yb,
                            float* __restrict__ da, float* __restrict__ db,
                            u32* __restrict__ Sz) {
  if (blockIdx.x == 0 && threadIdx.x < 4) Sz[threadIdx.x] = 0;  // S[0..2], cnt
  int row = blockIdx.x * 8 + (threadIdx.x >> 5);  // 32 lanes per row
  int l = threadIdx.x & 31;
  const float* src; u32* dst; float* dn; int r;
  if (row < N_PTS) { src = x; dst = xb; dn = da; r = row; }
  else             { src = y; dst = yb; dn = db; r = row - N_PTS; }
  float4 v = ((const float4*)(src + (size_t)r * 128))[l];
  u16 b0 = f32_to_bf16(v.x), b1 = f32_to_bf16(v.y);
  u16 b2 = f32_to_bf16(v.z), b3 = f32_to_bf16(v.w);
  float f0 = __uint_as_float((u32)b0 << 16), f1 = __uint_as_float((u32)b1 << 16);
  float f2 = __uint_as_float((u32)b2 << 16), f3 = __uint_as_float((u32)b3 << 16);
  float p = f0 * f0 + f1 * f1 + f2 * f2 + f3 * f3;
  uint2 pk;
  pk.x = (u32)b0 | ((u32)b1 << 16);
  pk.y = (u32)b2 | ((u32)b3 << 16);
  ((uint2*)(dst + (size_t)r * 64))[l] = pk;
#pragma unroll
  for (int off = 16; off; off >>= 1) p += __shfl_xor(p, off, 64);  // within 32
  if (l == 0) dn[r] = -LOG2E * p;
}

struct Job { int pair, rb, cc; };

__device__ __forceinline__ Job decode_job(int t) {
  Job jb;
  if (t < 2 * NSELF) {
    jb.pair = (t < NSELF) ? 0 : 1;
    int tt = t - jb.pair * NSELF;
    int r = 0;
    while (tt >= TJ - r) { tt -= TJ - r; r++; }
    jb.rb = r; jb.cc = r + tt;
  } else {
    int q = t - 2 * NSELF;
    jb.pair = 2; jb.rb = q >> 7; jb.cc = q & 127;
  }
  return jb;
}

__device__ __forceinline__ Job next_job(Job c) {
  Job n = c;
  if (c.cc < TJ - 1) { n.cc++; return n; }
  if (c.pair == 2) { n.rb++; n.cc = 0; return n; }  // guarded by hasNext
  if (c.rb == TJ - 1) { n.pair = c.pair + 1; n.rb = 0; n.cc = 0; return n; }
  n.rb = c.rb + 1; n.cc = n.rb; return n;
}

__device__ __forceinline__ const u16* selA(int p, const u16* xb, const u16* yb) {
  return (p == 1) ? yb : xb;
}
__device__ __forceinline__ const u16* selB(int p, const u16* xb, const u16* yb) {
  return (p == 0) ? xb : yb;
}

// A-frags (32x32x16: A[m=lane&31][k=(lane>>5)*8+j]) + conservative row-norm max
__device__ __forceinline__ void load_strip(const u16* A, const float* dA, int rb,
                                           int l31, int h,
                                           short8 afr[8][2], float damMax[2]) {
#pragma unroll
  for (int ks = 0; ks < 8; ks++)
#pragma unroll
    for (int mi = 0; mi < 2; mi++)
      afr[ks][mi] = *(const short8*)(A + (size_t)(rb * 64 + mi * 32 + l31) * 128 +
                                     ks * 16 + h * 8);
#pragma unroll
  for (int mi = 0; mi < 2; mi++) {
    float v = dA[rb * 64 + mi * 32 + l31];
#pragma unroll
    for (int off = 16; off; off >>= 1) v = fmaxf(v, __shfl_xor(v, off, 64));
    damMax[mi] = v;
  }
}

__global__ __launch_bounds__(256, 2) void mmd_kernel(
    const u16* __restrict__ xb, const u16* __restrict__ yb,
    const float* __restrict__ da, const float* __restrict__ db,
    float* __restrict__ S, u32* __restrict__ cnt, float* __restrict__ out) {
  int g = blockIdx.x * 4 + (threadIdx.x >> 6);
  int lane = threadIdx.x & 63;
  int l31 = lane & 31, h = lane >> 5;

  int start = (g * NT) >> 12;        // NWAVES = 4096
  int end = ((g + 1) * NT) >> 12;

  Job cur = decode_job(start);
  short8 afr[8][2];
  float damMax[2];
  load_strip(selA(cur.pair, xb, yb), (cur.pair == 1) ? db : da, cur.rb, l31, h,
             afr, damMax);

  // per-lane B element offsets (B[n=lane&31][k=(lane>>5)*8+j], row-major pts)
  int boff0 = l31 * 128 + h * 8;
  int boff1 = (32 + l31) * 128 + h * 8;
  const u16* Bt = selB(cur.pair, xb, yb) + (size_t)cur.cc * 8192;

  short8 bf[4][2];
  bf[0][0] = *(const short8*)(Bt + boff0);
  bf[0][1] = *(const short8*)(Bt + boff1);
  bf[1][0] = *(const short8*)(Bt + boff0 + 16);
  bf[1][1] = *(const short8*)(Bt + boff1 + 16);

  const float c1 = 2.0f * LOG2E;
  float tsum = 0.f;

  for (int j = start; j < end; j++) {
    bool hasNext = (j + 1 < end);
    Job nxt = cur;
    if (hasNext) nxt = next_job(cur);
    const u16* Bnxt = selB(nxt.pair, xb, yb) + (size_t)nxt.cc * 8192;

    const float* dBc = (cur.pair == 0) ? da : db;
    float dbn0 = dBc[cur.cc * 64 + l31];        // exact per-lane col norms
    float dbn1 = dBc[cur.cc * 64 + 32 + l31];

    floatx16 acc00, acc01, acc10, acc11;
#pragma unroll
    for (int i = 0; i < 16; i++) { acc00[i] = 0.f; acc01[i] = 0.f; acc10[i] = 0.f; acc11[i] = 0.f; }

#pragma unroll
    for (int ks = 0; ks < 8; ks++) {
      int s2 = (ks + 2) & 3;      // slot for prefetch (2 steps ahead)
      if (ks < 6) {
        bf[s2][0] = *(const short8*)(Bt + boff0 + (ks + 2) * 16);
        bf[s2][1] = *(const short8*)(Bt + boff1 + (ks + 2) * 16);
      } else if (hasNext) {       // cross-tile: next tile's steps 0,1
        bf[s2][0] = *(const short8*)(Bnxt + boff0 + (ks - 6) * 16);
        bf[s2][1] = *(const short8*)(Bnxt + boff1 + (ks - 6) * 16);
      }
      int s = ks & 3;
      acc00 = __builtin_amdgcn_mfma_f32_32x32x16_bf16(afr[ks][0], bf[s][0], acc00, 0, 0, 0);
      acc01 = __builtin_amdgcn_mfma_f32_32x32x16_bf16(afr[ks][0], bf[s][1], acc01, 0, 0, 0);
      acc10 = __builtin_amdgcn_mfma_f32_32x32x16_bf16(afr[ks][1], bf[s][0], acc10, 0, 0, 0);
      acc11 = __builtin_amdgcn_mfma_f32_32x32x16_bf16(afr[ks][1], bf[s][1], acc11, 0, 0, 0);
    }

    // ---- thresholded epilogue (exact path ~256/32896 tiles) ----
    {
      float w = (cur.pair < 2 && cur.rb != cur.cc) ? 2.0f : 1.0f;
      const float* dAc = (cur.pair == 1) ? db : da;
#define DO_FRAG(A_, MI_, DBN_)                                                  \
      {                                                                         \
        float mx = (A_)[0];                                                     \
        _Pragma("unroll")                                                       \
        for (int i = 1; i < 16; i++) mx = fmaxf(mx, (A_)[i]);                   \
        if (__any(fmaf(c1, mx, damMax[MI_] + (DBN_)) > THRESH)) {               \
          int rbase = cur.rb * 64 + (MI_) * 32 + 4 * h;                         \
          _Pragma("unroll")                                                     \
          for (int r = 0; r < 16; r++) {                                        \
            float dam = dAc[rbase + (r & 3) + 8 * (r >> 2)];                    \
            tsum = fmaf(w, EXP2(fmaf(c1, (A_)[r], dam + (DBN_))), tsum);        \
          }                                                                     \
        }                                                                       \
      }
      DO_FRAG(acc00, 0, dbn0)
      DO_FRAG(acc01, 0, dbn1)
      DO_FRAG(acc10, 1, dbn0)
      DO_FRAG(acc11, 1, dbn1)
#undef DO_FRAG
    }

    bool pairChange = hasNext && (nxt.pair != cur.pair);
    if (!hasNext || pairChange) {
      float r = tsum;
#pragma unroll
      for (int off = 32; off; off >>= 1) r += __shfl_down(r, off, 64);
      if (lane == 0) atomicAdd(&S[cur.pair], r);
      tsum = 0.f;
    }
    if (hasNext && (pairChange || nxt.rb != cur.rb))
      load_strip(selA(nxt.pair, xb, yb), (nxt.pair == 1) ? db : da, nxt.rb,
                 l31, h, afr, damMax);

    Bt = Bnxt;
    cur = nxt;
  }

  // ---- last finishing wave combines ----
  if (lane == 0) {
    __threadfence();
    u32 old = atomicAdd(cnt, 1u);
    if (old == (u32)(NWAVES - 1)) {
      float s0 = atomicAdd(&S[0], 0.0f);
      float s1 = atomicAdd(&S[1], 0.0f);
      float s2 = atomicAdd(&S[2], 0.0f);
      out[0] = (s0 + s1 - 2.0f * s2) * (1.0f / ((float)N_PTS * (float)N_PTS));
    }
  }
}

extern "C" void kernel_launch(void* const* d_in, const int* in_sizes, int n_in,
                              void* d_out, int out_size, void* d_ws, size_t ws_size,
                              hipStream_t stream) {
  const float* x = (const float*)d_in[0];
  const float* y = (const float*)d_in[1];
  char* ws = (char*)d_ws;
  float* S = (float*)ws;                                   // S[0..2], cnt
  u32* cnt = (u32*)ws + 3;
  u32* xb = (u32*)(ws + 256);                              // 2 MB bf16
  u32* yb = (u32*)(ws + 256 + 2097152);                    // 2 MB bf16
  float* da = (float*)(ws + 256 + 2 * 2097152);            // 32 KB
  float* db = (float*)(ws + 256 + 2 * 2097152 + 32768);    // 32 KB

  prep_kernel<<<2048, 256, 0, stream>>>(x, y, xb, yb, da, db, (u32*)ws);
  mmd_kernel<<<NBLOCKS, 256, 0, stream>>>((const u16*)xb, (const u16*)yb,
                                          da, db, S, cnt, (float*)d_out);
}

// Round 4
// 145.392 us; speedup vs baseline: 1.5337x; 1.5337x over previous
//
#include <hip/hip_runtime.h>

// MMD RBF loss, N=8192, D=128, gamma=1, fp32 in, fp32 scalar out.
// R4: R2's cooperative-LDS strip structure + AITER-style raw-barrier pipeline.
// Per step: s_waitcnt vmcnt(0) [stage j, issued a full step ago] -> raw
// s_barrier -> issue stage j+1 (global_load_lds) into the buffer the barrier
// just freed -> compute tile j. No __syncthreads, so no compiler-forced drain
// of in-flight prefetch. 32x32x16 bf16 MFMA, wave=64x64, block=128x128.

#define N_PTS 8192
#define TJ 64          // 8192/128 tiles per side
#define NSELF 2080     // 64*65/2
#define NJOBS 8256     // 2*2080 + 4096
#define NBLOCKS 512
#define NWAVES (NBLOCKS * 4)
#define LOG2E 1.4426950408889634f
#define THRESH -40.0f
#define WAITCNT_VM0 0x0F70   // vmcnt(0), lgkmcnt=15 (no wait), expcnt=7

typedef __attribute__((ext_vector_type(8))) short short8;    // 8 bf16
typedef __attribute__((ext_vector_type(16))) float floatx16; // 32x32 acc
typedef unsigned int u32;
typedef unsigned short u16;

#if __has_builtin(__builtin_amdgcn_exp2f)
#define EXP2(x) __builtin_amdgcn_exp2f(x)
#else
#define EXP2(x) exp2f(x)
#endif

__device__ __forceinline__ u16 f32_to_bf16(float f) {
  u32 u = __float_as_uint(f);
  u32 r = (u + 0x7fffu + ((u >> 16) & 1u)) >> 16;  // RNE
  return (u16)r;
}

__device__ __forceinline__ void gl_lds16(const u16* g, u16* l) {
  __builtin_amdgcn_global_load_lds(
      (const __attribute__((address_space(1))) u32*)g,
      (__attribute__((address_space(3))) u32*)l, 16, 0, 0);
}

// ---- prep: fp32 -> bf16 (RNE) + per-row d = -log2e*sum(xb^2); zero S/cnt ----
__global__ void prep_kernel(const float* __restrict__ x, const float* __restrict__ y,
                            u32* __restrict__ xb, u32* __restrict__ yb,
                            float* __restrict__ da, float* __restrict__ db,
                            u32* __restrict__ Sz) {
  if (blockIdx.x == 0 && threadIdx.x < 4) Sz[threadIdx.x] = 0;  // S[0..2], cnt
  int row = blockIdx.x * 8 + (threadIdx.x >> 5);  // 32 lanes per row
  int l = threadIdx.x & 31;
  const float* src; u32* dst; float* dn; int r;
  if (row < N_PTS) { src = x; dst = xb; dn = da; r = row; }
  else             { src = y; dst = yb; dn = db; r = row - N_PTS; }
  float4 v = ((const float4*)(src + (size_t)r * 128))[l];
  u16 b0 = f32_to_bf16(v.x), b1 = f32_to_bf16(v.y);
  u16 b2 = f32_to_bf16(v.z), b3 = f32_to_bf16(v.w);
  float f0 = __uint_as_float((u32)b0 << 16), f1 = __uint_as_float((u32)b1 << 16);
  float f2 = __uint_as_float((u32)b2 << 16), f3 = __uint_as_float((u32)b3 << 16);
  float p = f0 * f0 + f1 * f1 + f2 * f2 + f3 * f3;
  uint2 pk;
  pk.x = (u32)b0 | ((u32)b1 << 16);
  pk.y = (u32)b2 | ((u32)b3 << 16);
  ((uint2*)(dst + (size_t)r * 64))[l] = pk;
#pragma unroll
  for (int off = 16; off; off >>= 1) p += __shfl_xor(p, off, 64);
  if (l == 0) dn[r] = -LOG2E * p;
}

struct Job { int pair, rr, cc; };

__device__ __forceinline__ Job decode_job(int t) {
  Job jb;
  if (t < 2 * NSELF) {
    jb.pair = (t < NSELF) ? 0 : 1;
    int tt = t - jb.pair * NSELF;
    int r = 0;
    while (tt >= TJ - r) { tt -= TJ - r; r++; }
    jb.rr = r; jb.cc = r + tt;
  } else {
    int q = t - 2 * NSELF;
    jb.pair = 2; jb.rr = q >> 6; jb.cc = q & 63;
  }
  return jb;
}

__device__ __forceinline__ Job next_job(Job c) {
  Job n = c;
  if (c.cc < TJ - 1) { n.cc++; return n; }
  if (c.pair == 2) { n.rr++; n.cc = 0; return n; }
  if (c.rr == TJ - 1) { n.pair = c.pair + 1; n.rr = 0; n.cc = 0; return n; }
  n.rr = c.rr + 1; n.cc = n.rr; return n;
}

__device__ __forceinline__ const u16* selA(int p, const u16* xb, const u16* yb) {
  return (p == 1) ? yb : xb;
}
__device__ __forceinline__ const u16* selB(int p, const u16* xb, const u16* yb) {
  return (p == 0) ? xb : yb;
}

// cooperative staging: 32 KB B tile, 8 insts/wave, XOR-16B-chunk swizzle
__device__ __forceinline__ void stage_tile(const u16* gsrc, u16* ldst,
                                           int wid, int q16, int l15) {
#pragma unroll
  for (int i = 0; i < 8; i++) {
    int ch = wid * 8 + i;
    int lrow = ch * 4 + q16;
    int bsw = l15 ^ (lrow & 15);
    gl_lds16(gsrc + lrow * 128 + bsw * 8, ldst + ch * 512);
  }
}

// A-frags (32x32x16: A[m=l31 per frag][k=h*8+j]) + conservative row-norm max
__device__ __forceinline__ void load_strip(const u16* A, const float* dA, int rr,
                                           int mgroup, int l31, int h,
                                           short8 afr[8][2], float damMax[2]) {
  int rbase = rr * 128 + mgroup * 64;
#pragma unroll
  for (int ks = 0; ks < 8; ks++)
#pragma unroll
    for (int mi = 0; mi < 2; mi++)
      afr[ks][mi] = *(const short8*)(A + (size_t)(rbase + mi * 32 + l31) * 128 +
                                     ks * 16 + h * 8);
#pragma unroll
  for (int mi = 0; mi < 2; mi++) {
    float v = dA[rbase + mi * 32 + l31];
#pragma unroll
    for (int off = 16; off; off >>= 1) v = fmaxf(v, __shfl_xor(v, off, 64));
    damMax[mi] = v;
  }
}

__global__ __launch_bounds__(256, 2) void mmd_kernel(
    const u16* __restrict__ xb, const u16* __restrict__ yb,
    const float* __restrict__ da, const float* __restrict__ db,
    float* __restrict__ S, u32* __restrict__ cnt, float* __restrict__ out) {
  __shared__ u16 Bt[2][128 * 128];  // 2 x 32 KB ping-pong

  int tid = threadIdx.x;
  int wid = tid >> 6, lane = tid & 63;
  int l31 = lane & 31, h = lane >> 5;
  int q16 = lane >> 4, l15 = lane & 15;
  int mgroup = wid >> 1, ngroup = wid & 1;

  int start = (blockIdx.x * NJOBS) >> 9;   // NBLOCKS = 512
  int end = ((blockIdx.x + 1) * NJOBS) >> 9;

  Job jc = decode_job(start);
  short8 afr[8][2];
  float damMax[2];
  load_strip(selA(jc.pair, xb, yb), (jc.pair == 1) ? db : da, jc.rr,
             mgroup, l31, h, afr, damMax);
  stage_tile(selB(jc.pair, xb, yb) + (size_t)jc.cc * 16384, &Bt[0][0],
             wid, q16, l15);

  const float c1 = 2.0f * LOG2E;
  float tsum = 0.f;
  int p = 0;

  for (int j = start; j < end; j++) {
    bool hasNext = (j + 1 < end);
    Job jn = jc;
    if (hasNext) jn = next_job(jc);

    // wait for Bt[p] (staged one full step ago), then raw barrier (no drain
    // of anything issued after), then immediately prefetch step j+1 into the
    // buffer the barrier just freed.
    __builtin_amdgcn_s_waitcnt(WAITCNT_VM0);
    __asm__ __volatile__("" ::: "memory");
    __builtin_amdgcn_s_barrier();
    __asm__ __volatile__("" ::: "memory");
    if (hasNext)
      stage_tile(selB(jn.pair, xb, yb) + (size_t)jn.cc * 16384, &Bt[p ^ 1][0],
                 wid, q16, l15);

    const float* dBc = (jc.pair == 0) ? da : db;
    float dbn0 = dBc[jc.cc * 128 + ngroup * 64 + l31];
    float dbn1 = dBc[jc.cc * 128 + ngroup * 64 + 32 + l31];

    floatx16 acc00, acc01, acc10, acc11;
#pragma unroll
    for (int i = 0; i < 16; i++) {
      acc00[i] = 0.f; acc01[i] = 0.f; acc10[i] = 0.f; acc11[i] = 0.f;
    }

#pragma unroll
    for (int ks = 0; ks < 8; ks++) {
      short8 bf0, bf1;
      {
        int row0 = ngroup * 64 + l31;
        int row1 = ngroup * 64 + 32 + l31;
        int c = ks * 2 + h;
        bf0 = *(const short8*)(&Bt[p][row0 * 128 + ((c ^ (row0 & 15)) * 8)]);
        bf1 = *(const short8*)(&Bt[p][row1 * 128 + ((c ^ (row1 & 15)) * 8)]);
      }
      acc00 = __builtin_amdgcn_mfma_f32_32x32x16_bf16(afr[ks][0], bf0, acc00, 0, 0, 0);
      acc01 = __builtin_amdgcn_mfma_f32_32x32x16_bf16(afr[ks][0], bf1, acc01, 0, 0, 0);
      acc10 = __builtin_amdgcn_mfma_f32_32x32x16_bf16(afr[ks][1], bf0, acc10, 0, 0, 0);
      acc11 = __builtin_amdgcn_mfma_f32_32x32x16_bf16(afr[ks][1], bf1, acc11, 0, 0, 0);
    }

    // ---- thresholded epilogue (exact exp path only near the diagonal) ----
    {
      float w = (jc.pair < 2 && jc.rr != jc.cc) ? 2.0f : 1.0f;
      const float* dAc = (jc.pair == 1) ? db : da;
      int rstrip = jc.rr * 128 + mgroup * 64;
#define DO_FRAG(A_, MI_, DBN_)                                                  \
      {                                                                         \
        float mx = (A_)[0];                                                     \
        _Pragma("unroll")                                                       \
        for (int i = 1; i < 16; i++) mx = fmaxf(mx, (A_)[i]);                   \
        if (__any(fmaf(c1, mx, damMax[MI_] + (DBN_)) > THRESH)) {               \
          int rbase = rstrip + (MI_) * 32 + 4 * h;                              \
          _Pragma("unroll")                                                     \
          for (int r = 0; r < 16; r++) {                                        \
            float dam = dAc[rbase + (r & 3) + 8 * (r >> 2)];                    \
            tsum = fmaf(w, EXP2(fmaf(c1, (A_)[r], dam + (DBN_))), tsum);        \
          }                                                                     \
        }                                                                       \
      }
      DO_FRAG(acc00, 0, dbn0)
      DO_FRAG(acc01, 0, dbn1)
      DO_FRAG(acc10, 1, dbn0)
      DO_FRAG(acc11, 1, dbn1)
#undef DO_FRAG
    }

    bool pairChange = hasNext && (jn.pair != jc.pair);
    if (!hasNext || pairChange) {
      float r = tsum;
#pragma unroll
      for (int off = 32; off; off >>= 1) r += __shfl_down(r, off, 64);
      if (lane == 0) atomicAdd(&S[jc.pair], r);
      tsum = 0.f;
    }
    if (hasNext && (pairChange || jn.rr != jc.rr))
      load_strip(selA(jn.pair, xb, yb), (jn.pair == 1) ? db : da, jn.rr,
                 mgroup, l31, h, afr, damMax);

    p ^= 1;
    jc = jn;
  }

  // ---- last finishing wave combines ----
  if (lane == 0) {
    __threadfence();
    u32 old = atomicAdd(cnt, 1u);
    if (old == (u32)(NWAVES - 1)) {
      float s0 = atomicAdd(&S[0], 0.0f);
      float s1 = atomicAdd(&S[1], 0.0f);
      float s2 = atomicAdd(&S[2], 0.0f);
      out[0] = (s0 + s1 - 2.0f * s2) * (1.0f / ((float)N_PTS * (float)N_PTS));
    }
  }
}

extern "C" void kernel_launch(void* const* d_in, const int* in_sizes, int n_in,
                              void* d_out, int out_size, void* d_ws, size_t ws_size,
                              hipStream_t stream) {
  const float* x = (const float*)d_in[0];
  const float* y = (const float*)d_in[1];
  char* ws = (char*)d_ws;
  float* S = (float*)ws;                                   // S[0..2], cnt
  u32* cnt = (u32*)ws + 3;
  u32* xb = (u32*)(ws + 256);                              // 2 MB bf16
  u32* yb = (u32*)(ws + 256 + 2097152);                    // 2 MB bf16
  float* da = (float*)(ws + 256 + 2 * 2097152);            // 32 KB
  float* db = (float*)(ws + 256 + 2 * 2097152 + 32768);    // 32 KB

  prep_kernel<<<2048, 256, 0, stream>>>(x, y, xb, yb, da, db, (u32*)ws);
  mmd_kernel<<<NBLOCKS, 256, 0, stream>>>((const u16*)xb, (const u16*)yb,
                                          da, db, S, cnt, (float*)d_out);
}